// Round 1
// baseline (155.834 us; speedup 1.0000x reference)
//
#include <hip/hip_runtime.h>
#include <hip/hip_bf16.h>

typedef unsigned short ushort_t;
using ushort4v = __attribute__((ext_vector_type(4))) ushort_t;
using ushort8 = __attribute__((ext_vector_type(8))) ushort_t;
using short8  = __attribute__((ext_vector_type(8))) short;
using float4v = __attribute__((ext_vector_type(4))) float;

#define Bsz 256
#define Aattr 32
#define Ddim 2048

__device__ __forceinline__ float bf2f(ushort_t u) {
    union { unsigned int i; float f; } c;
    c.i = ((unsigned int)u) << 16;
    return c.f;
}

__device__ __forceinline__ ushort_t f2bf(float f) {
    union { float f; unsigned int i; } c;
    c.f = f;
    unsigned int x = c.i;
    unsigned int r = (x + 0x7FFFu + ((x >> 16) & 1u)) >> 16;  // RNE
    return (ushort_t)r;
}

struct BfPair { ushort_t hi, lo; };
__device__ __forceinline__ BfPair split_bf16(float x) {
    BfPair p;
    p.hi = f2bf(x);
    p.lo = f2bf(x - bf2f(p.hi));
    return p;
}

// ---------------------------------------------------------------------------
// Kernel 1 (fused prep): two independent BW-bound jobs in one dispatch.
//   blocks [0, 512):   masked attribute reduction -> s_hi/s_lo
//   blocks [512,1536): W fp32 [d][e] -> WT_hi/WT_lo bf16 [e][d] (64x64 tiles)
// (unchanged from previous version — HBM-bound at ~10.5 us for ~66 MB)
// ---------------------------------------------------------------------------
__global__ __launch_bounds__(256) void k_prep(
    const float* __restrict__ feat, const int* __restrict__ label,
    const float* __restrict__ W,
    ushort_t* __restrict__ s_hi, ushort_t* __restrict__ s_lo,
    ushort_t* __restrict__ WT_hi, ushort_t* __restrict__ WT_lo) {
    __shared__ float tile[64][65];   // wt path; reduce path reuses as int[]
    const int t = threadIdx.x;

    if (blockIdx.x < 512) {
        // ---- reduce path: b = id>>1, half = id&1 ----
        int* list = (int*)&tile[0][0];
        int* cntp = (int*)&tile[1][0];
        const int b    = blockIdx.x >> 1;
        const int half = blockIdx.x & 1;

        if (t < 64) {
            int lab = label[b * Aattr + (t & 31)];
            unsigned long long vote = __ballot(lab > 0);
            unsigned m32 = (unsigned)(vote & 0xFFFFFFFFull);
            if (t < 32) {
                if (lab > 0) {
                    int rank = __popc(m32 & ((1u << t) - 1u));
                    list[rank] = t;
                }
                if (t == 0) *cntp = __popc(m32);
            }
        }
        __syncthreads();

        const int n  = *cntp;
        const int d0 = half * 1024 + t * 4;
        const float* fb = feat + (size_t)b * (Aattr * Ddim) + d0;

        float a0 = 0.f, a1 = 0.f, a2 = 0.f, a3 = 0.f;
        int i = 0;
        for (; i + 4 <= n; i += 4) {
            const int j0 = list[i], j1 = list[i+1], j2 = list[i+2], j3 = list[i+3];
            float4 v0 = *(const float4*)(fb + j0 * Ddim);
            float4 v1 = *(const float4*)(fb + j1 * Ddim);
            float4 v2 = *(const float4*)(fb + j2 * Ddim);
            float4 v3 = *(const float4*)(fb + j3 * Ddim);
            a0 += v0.x + v1.x + v2.x + v3.x;
            a1 += v0.y + v1.y + v2.y + v3.y;
            a2 += v0.z + v1.z + v2.z + v3.z;
            a3 += v0.w + v1.w + v2.w + v3.w;
        }
        for (; i < n; ++i) {
            float4 v = *(const float4*)(fb + list[i] * Ddim);
            a0 += v.x; a1 += v.y; a2 += v.z; a3 += v.w;
        }

        ushort4v hi, lo;
        BfPair p0 = split_bf16(a0); hi[0] = p0.hi; lo[0] = p0.lo;
        BfPair p1 = split_bf16(a1); hi[1] = p1.hi; lo[1] = p1.lo;
        BfPair p2 = split_bf16(a2); hi[2] = p2.hi; lo[2] = p2.lo;
        BfPair p3 = split_bf16(a3); hi[3] = p3.hi; lo[3] = p3.lo;
        *(ushort4v*)(s_hi + (size_t)b * Ddim + d0) = hi;
        *(ushort4v*)(s_lo + (size_t)b * Ddim + d0) = lo;
    } else {
        // ---- transpose+split path ----
        const int q  = blockIdx.x - 512;
        const int bx = q & 31;        // e-tile
        const int by = q >> 5;        // d-tile

#pragma unroll
        for (int p = 0; p < 4; ++p) {
            const int row = p * 16 + (t >> 4);
            const int c   = (t & 15) * 4;
            float4 v = *(const float4*)(W + (size_t)(by * 64 + row) * Ddim + bx * 64 + c);
            tile[row][c + 0] = v.x;
            tile[row][c + 1] = v.y;
            tile[row][c + 2] = v.z;
            tile[row][c + 3] = v.w;
        }
        __syncthreads();
#pragma unroll
        for (int p = 0; p < 2; ++p) {
            const int er = p * 32 + (t >> 3);
            const int dc = (t & 7) * 8;
            ushort8 hi, lo;
#pragma unroll
            for (int j = 0; j < 8; ++j) {
                BfPair pr = split_bf16(tile[dc + j][er]);
                hi[j] = pr.hi; lo[j] = pr.lo;
            }
            const size_t off = (size_t)(bx * 64 + er) * Ddim + by * 64 + dc;
            *(ushort8*)(WT_hi + off) = hi;
            *(ushort8*)(WT_lo + off) = lo;
        }
    }
}

// ---------------------------------------------------------------------------
// Kernel 2: fused GEMM + K-reduce + bias + tanh.
// NEW GEOMETRY vs previous version: 128 blocks x 8 waves, block tile 64(m)x64(n).
//   - Per-wave work is byte/instruction-identical to before (32m x 64n x 512k,
//     3-term emulated-fp32 MFMA), but the two m-halves of a 64-row tile now
//     live in the SAME block: waves (wm, wk) with wm=m-half, wk=K-chunk.
//   - Why: gemm2 is L2-BW-bound, not MFMA-bound (MFMA wall ~0.8 us/wave).
//     Cross-block read cost = #m_tiles*16MB(B) + #n_tiles*2MB(A).
//     m-tile 32->64 rows: 8*16+32*2=192MB -> 4*16+32*2=128MB of L2 reads,
//     and the wm=0/wm=1 waves read identical B-frag addresses on one CU in
//     near-lockstep -> L1 (32KB ~= 4 K-steps of B) serves the duplicate.
//   - Swizzle: XCD = g&7 (round-robin dispatch), q=g>>3: n_tile=(g&7)*4+(q&3),
//     m_tile=q>>2 -> per XCD 4 n-tiles x 4 m-tiles; unique B/XCD = 2MB +
//     unique A/XCD = 2MB = 4MB L2.
//   - red stride padded 64->68 floats (272B, float4-aligned) to break the
//     4-way dump / 8-way reduce bank conflicts of the old stride-64 layout.
// ---------------------------------------------------------------------------
__global__ __launch_bounds__(512) void k_gemm2(
    const ushort_t* __restrict__ S_hi, const ushort_t* __restrict__ S_lo,
    const ushort_t* __restrict__ WT_hi, const ushort_t* __restrict__ WT_lo,
    const float* __restrict__ bias, float* __restrict__ out) {
    __shared__ float red[8][32 * 68];   // 69632 B

    const int g      = blockIdx.x;
    const int q      = g >> 3;
    const int n_tile = (g & 7) * 4 + (q & 3);
    const int m_tile = q >> 2;
    const int m0     = m_tile * 64;
    const int n0     = n_tile * 64;

    const int t    = threadIdx.x;
    const int w    = t >> 6;          // wave id 0..7
    const int wm   = w >> 2;          // m-half 0..1
    const int wk   = w & 3;           // K-chunk 0..3
    const int l    = t & 63;
    const int quad = l >> 4;
    const int m16  = l & 15;
    const int k0   = wk * 512;

    float4v acc[2][4];
#pragma unroll
    for (int i = 0; i < 2; ++i)
#pragma unroll
        for (int j = 0; j < 4; ++j) acc[i][j] = {0.f, 0.f, 0.f, 0.f};

    // A-frag: lane holds A[m=m16][k=quad*8+j]; B-frag mirrored (n=m16).
    const size_t aoff = (size_t)(m0 + wm * 32 + m16) * Ddim + quad * 8;
    const size_t boff = (size_t)(n0 + m16) * Ddim + quad * 8;
    const ushort_t* Ah = S_hi + aoff;
    const ushort_t* Al = S_lo + aoff;
    const ushort_t* Bh = WT_hi + boff;
    const ushort_t* Bl = WT_lo + boff;

    for (int k = k0; k < k0 + 512; k += 32) {
        short8 ah0 = *(const short8*)(Ah + k);
        short8 ah1 = *(const short8*)(Ah + 16 * Ddim + k);
        short8 al0 = *(const short8*)(Al + k);
        short8 al1 = *(const short8*)(Al + 16 * Ddim + k);
        short8 bh[4], bl[4];
#pragma unroll
        for (int i = 0; i < 4; ++i) {
            const size_t o = (size_t)(i * 16) * Ddim + k;
            bh[i] = *(const short8*)(Bh + o);
            bl[i] = *(const short8*)(Bl + o);
        }
#pragma unroll
        for (int ni = 0; ni < 4; ++ni) {
            acc[0][ni] = __builtin_amdgcn_mfma_f32_16x16x32_bf16(ah0, bh[ni], acc[0][ni], 0, 0, 0);
            acc[0][ni] = __builtin_amdgcn_mfma_f32_16x16x32_bf16(ah0, bl[ni], acc[0][ni], 0, 0, 0);
            acc[0][ni] = __builtin_amdgcn_mfma_f32_16x16x32_bf16(al0, bh[ni], acc[0][ni], 0, 0, 0);
            acc[1][ni] = __builtin_amdgcn_mfma_f32_16x16x32_bf16(ah1, bh[ni], acc[1][ni], 0, 0, 0);
            acc[1][ni] = __builtin_amdgcn_mfma_f32_16x16x32_bf16(ah1, bl[ni], acc[1][ni], 0, 0, 0);
            acc[1][ni] = __builtin_amdgcn_mfma_f32_16x16x32_bf16(al1, bh[ni], acc[1][ni], 0, 0, 0);
        }
    }

    // dump wave tiles to LDS (C/D layout: col(n)=lane&15, row(m)=quad*4+reg)
#pragma unroll
    for (int mi = 0; mi < 2; ++mi) {
#pragma unroll
        for (int ni = 0; ni < 4; ++ni) {
#pragma unroll
            for (int rr = 0; rr < 4; ++rr) {
                red[w][(mi * 16 + quad * 4 + rr) * 68 + ni * 16 + m16] = acc[mi][ni][rr];
            }
        }
    }
    __syncthreads();

    // reduce the 4 wk-waves of each m-half + bias + tanh.
    // thread t -> block-row m_l = t>>3 (0..63), n_l = (t&7)*8
    const int m_l  = t >> 3;
    const int n_l  = (t & 7) * 8;
    const int half = m_l >> 5;
    const int base = (m_l & 31) * 68 + n_l;
    float s[8];
#pragma unroll
    for (int j = 0; j < 8; ++j) s[j] = 0.f;
#pragma unroll
    for (int ww = 0; ww < 4; ++ww) {
        float4 v0 = *(const float4*)&red[half * 4 + ww][base];
        float4 v1 = *(const float4*)&red[half * 4 + ww][base + 4];
        s[0] += v0.x; s[1] += v0.y; s[2] += v0.z; s[3] += v0.w;
        s[4] += v1.x; s[5] += v1.y; s[6] += v1.z; s[7] += v1.w;
    }
    float4 b0 = *(const float4*)(bias + n0 + n_l);
    float4 b1 = *(const float4*)(bias + n0 + n_l + 4);
    float4 o0, o1;
    o0.x = tanhf(s[0] + b0.x);
    o0.y = tanhf(s[1] + b0.y);
    o0.z = tanhf(s[2] + b0.z);
    o0.w = tanhf(s[3] + b0.w);
    o1.x = tanhf(s[4] + b1.x);
    o1.y = tanhf(s[5] + b1.y);
    o1.z = tanhf(s[6] + b1.z);
    o1.w = tanhf(s[7] + b1.w);
    float* op = out + (size_t)(m0 + m_l) * Ddim + n0 + n_l;
    *(float4*)op = o0;
    *(float4*)(op + 4) = o1;
}

extern "C" void kernel_launch(void* const* d_in, const int* in_sizes, int n_in,
                              void* d_out, int out_size, void* d_ws, size_t ws_size,
                              hipStream_t stream) {
    // inputs (fp32 unless noted): x (dead for returned row), feat[256*32*2048],
    // label[256*32] (int32 — JAX x64 disabled), W[2048*2048], b[2048]
    const float* feat  = (const float*)d_in[1];
    const int*   label = (const int*)d_in[2];
    const float* W     = (const float*)d_in[3];
    const float* bias  = (const float*)d_in[4];
    float*       out   = (float*)d_out;

    char* ws = (char*)d_ws;
    ushort_t* s_hi  = (ushort_t*)ws;                 // 1 MB
    ushort_t* s_lo  = (ushort_t*)(ws + (1u << 20));  // 1 MB
    ushort_t* WT_hi = (ushort_t*)(ws + (2u << 20));  // 8 MB
    ushort_t* WT_lo = (ushort_t*)(ws + (10u << 20)); // 8 MB

    k_prep<<<dim3(1536), dim3(256), 0, stream>>>(feat, label, W, s_hi, s_lo, WT_hi, WT_lo);
    k_gemm2<<<dim3(128), dim3(512), 0, stream>>>(s_hi, s_lo, WT_hi, WT_lo, bias, out);
}

// Round 2
// 128.486 us; speedup vs baseline: 1.2129x; 1.2129x over previous
//
#include <hip/hip_runtime.h>
#include <hip/hip_bf16.h>

typedef unsigned short ushort_t;
using ushort4v = __attribute__((ext_vector_type(4))) ushort_t;
using ushort8 = __attribute__((ext_vector_type(8))) ushort_t;
using short8  = __attribute__((ext_vector_type(8))) short;
using float4v = __attribute__((ext_vector_type(4))) float;

#define Bsz 256
#define Aattr 32
#define Ddim 2048

// Tiled operand layout ("fragment-ordered"): X_t[row/16][k/32][16][32] bf16.
// Element (row r, k c) lives at ((r>>4)*(Ddim/32) + (c>>5))*512 + (r&15)*32 + (c&31).
// A wave's MFMA frag load (lane = m16,quad reads [m16][quad*8+j]) is then ONE
// contiguous 1KB transaction instead of 16 lines scattered at 4KB stride
// (which all alias the same L2 channel -> the round-1 latency pathology).
#define KT (Ddim / 32)          // 64 k-tiles per 16-row tile
#define ROWTILE (KT * 512)      // elements per 16-row tile = 32768

__device__ __forceinline__ float bf2f(ushort_t u) {
    union { unsigned int i; float f; } c;
    c.i = ((unsigned int)u) << 16;
    return c.f;
}

__device__ __forceinline__ ushort_t f2bf(float f) {
    union { float f; unsigned int i; } c;
    c.f = f;
    unsigned int x = c.i;
    unsigned int r = (x + 0x7FFFu + ((x >> 16) & 1u)) >> 16;  // RNE
    return (ushort_t)r;
}

struct BfPair { ushort_t hi, lo; };
__device__ __forceinline__ BfPair split_bf16(float x) {
    BfPair p;
    p.hi = f2bf(x);
    p.lo = f2bf(x - bf2f(p.hi));
    return p;
}

__device__ __forceinline__ size_t tiled_off(int row, int k) {
    return (size_t)((row >> 4) * KT + (k >> 5)) * 512 + (row & 15) * 32 + (k & 31);
}

// ---------------------------------------------------------------------------
// Kernel 1 (fused prep): two independent BW-bound jobs in one dispatch.
//   blocks [0, 512):   masked attribute reduction -> S hi/lo (tiled layout)
//   blocks [512,1536): W fp32 [d][e] -> WT hi/lo bf16 tiled [e-tiles][k-tiles]
// ---------------------------------------------------------------------------
__global__ __launch_bounds__(256) void k_prep(
    const float* __restrict__ feat, const int* __restrict__ label,
    const float* __restrict__ W,
    ushort_t* __restrict__ s_hi, ushort_t* __restrict__ s_lo,
    ushort_t* __restrict__ WT_hi, ushort_t* __restrict__ WT_lo) {
    __shared__ float tile[64][65];   // wt path; reduce path reuses as int[]
    const int t = threadIdx.x;

    if (blockIdx.x < 512) {
        // ---- reduce path: b = id>>1, half = id&1 ----
        int* list = (int*)&tile[0][0];
        int* cntp = (int*)&tile[1][0];
        const int b    = blockIdx.x >> 1;
        const int half = blockIdx.x & 1;

        if (t < 64) {
            int lab = label[b * Aattr + (t & 31)];
            unsigned long long vote = __ballot(lab > 0);
            unsigned m32 = (unsigned)(vote & 0xFFFFFFFFull);
            if (t < 32) {
                if (lab > 0) {
                    int rank = __popc(m32 & ((1u << t) - 1u));
                    list[rank] = t;
                }
                if (t == 0) *cntp = __popc(m32);
            }
        }
        __syncthreads();

        const int n  = *cntp;
        const int d0 = half * 1024 + t * 4;
        const float* fb = feat + (size_t)b * (Aattr * Ddim) + d0;

        float a0 = 0.f, a1 = 0.f, a2 = 0.f, a3 = 0.f;
        int i = 0;
        for (; i + 4 <= n; i += 4) {
            const int j0 = list[i], j1 = list[i+1], j2 = list[i+2], j3 = list[i+3];
            float4 v0 = *(const float4*)(fb + j0 * Ddim);
            float4 v1 = *(const float4*)(fb + j1 * Ddim);
            float4 v2 = *(const float4*)(fb + j2 * Ddim);
            float4 v3 = *(const float4*)(fb + j3 * Ddim);
            a0 += v0.x + v1.x + v2.x + v3.x;
            a1 += v0.y + v1.y + v2.y + v3.y;
            a2 += v0.z + v1.z + v2.z + v3.z;
            a3 += v0.w + v1.w + v2.w + v3.w;
        }
        for (; i < n; ++i) {
            float4 v = *(const float4*)(fb + list[i] * Ddim);
            a0 += v.x; a1 += v.y; a2 += v.z; a3 += v.w;
        }

        ushort4v hi, lo;
        BfPair p0 = split_bf16(a0); hi[0] = p0.hi; lo[0] = p0.lo;
        BfPair p1 = split_bf16(a1); hi[1] = p1.hi; lo[1] = p1.lo;
        BfPair p2 = split_bf16(a2); hi[2] = p2.hi; lo[2] = p2.lo;
        BfPair p3 = split_bf16(a3); hi[3] = p3.hi; lo[3] = p3.lo;
        const size_t off = tiled_off(b, d0);   // d0..d0+3 stay in one 32-k tile
        *(ushort4v*)(s_hi + off) = hi;
        *(ushort4v*)(s_lo + off) = lo;
    } else {
        // ---- transpose+split path ----
        const int q  = blockIdx.x - 512;
        const int bx = q & 31;        // e-tile
        const int by = q >> 5;        // d-tile

#pragma unroll
        for (int p = 0; p < 4; ++p) {
            const int row = p * 16 + (t >> 4);
            const int c   = (t & 15) * 4;
            float4 v = *(const float4*)(W + (size_t)(by * 64 + row) * Ddim + bx * 64 + c);
            tile[row][c + 0] = v.x;
            tile[row][c + 1] = v.y;
            tile[row][c + 2] = v.z;
            tile[row][c + 3] = v.w;
        }
        __syncthreads();
#pragma unroll
        for (int p = 0; p < 2; ++p) {
            const int er = p * 32 + (t >> 3);
            const int dc = (t & 7) * 8;
            ushort8 hi, lo;
#pragma unroll
            for (int j = 0; j < 8; ++j) {
                BfPair pr = split_bf16(tile[dc + j][er]);
                hi[j] = pr.hi; lo[j] = pr.lo;
            }
            // row e = bx*64+er, k = by*64+dc (8 consecutive k in one 32-tile)
            const size_t off = tiled_off(bx * 64 + er, by * 64 + dc);
            *(ushort8*)(WT_hi + off) = hi;
            *(ushort8*)(WT_lo + off) = lo;
        }
    }
}

// ---------------------------------------------------------------------------
// Kernel 2: fused GEMM + K-reduce + bias + tanh.
// Geometry: 256 blocks (all CUs) x 8 waves (512 thr). Block tile 32(m)x64(n),
// K-split 8 across waves (wave K-chunk = 256 = 8 MFMA steps of 32).
//   - Operands in fragment-ordered tiles: every frag load = contiguous 1KB.
//   - Register double-buffer prefetch: K-step it+1 issued before MFMAs of it
//     (static buffer index under full unroll -> stays in VGPRs, counted vmcnt).
//   - XCD swizzle: xcd=g&7 owns n_tiles [xcd*4, xcd*4+4) x all 8 m_tiles ->
//     unique working set 2MB(B) + 2MB(A) = 4MB = one XCD's L2.
//   - red stride 68 floats breaks dump/reduce bank conflicts.
// ---------------------------------------------------------------------------
__global__ __launch_bounds__(512, 2) void k_gemm2(
    const ushort_t* __restrict__ S_hi, const ushort_t* __restrict__ S_lo,
    const ushort_t* __restrict__ WT_hi, const ushort_t* __restrict__ WT_lo,
    const float* __restrict__ bias, float* __restrict__ out) {
    __shared__ float red[8][32 * 68];   // 69632 B

    const int g      = blockIdx.x;
    const int q      = g >> 3;
    const int n_tile = (g & 7) * 4 + (q & 3);   // [0,32)
    const int m_tile = q >> 2;                  // [0,8)
    const int m0     = m_tile * 32;
    const int n0     = n_tile * 64;

    const int t    = threadIdx.x;
    const int w    = t >> 6;          // wave id 0..7 = K-chunk
    const int l    = t & 63;
    const int quad = l >> 4;
    const int m16  = l & 15;

    float4v acc[2][4];
#pragma unroll
    for (int i = 0; i < 2; ++i)
#pragma unroll
        for (int j = 0; j < 4; ++j) acc[i][j] = {0.f, 0.f, 0.f, 0.f};

    // Wave base pointers into tiled operands. kt0 = w*8 (8 k-tiles per wave).
    const int lane_off = m16 * 32 + quad * 8;
    const size_t abase = (size_t)((m0 >> 4) * KT + w * 8) * 512 + lane_off;
    const size_t bbase = (size_t)((n0 >> 4) * KT + w * 8) * 512 + lane_off;
    const ushort_t* pAh = S_hi + abase;
    const ushort_t* pAl = S_lo + abase;
    const ushort_t* pBh = WT_hi + bbase;
    const ushort_t* pBl = WT_lo + bbase;

    short8 Ah_[2][2], Al_[2][2], Bh_[2][4], Bl_[2][4];

#define LOADSET(buf, it)                                                     \
    do {                                                                     \
        Ah_[buf][0] = *(const short8*)(pAh + (it) * 512);                    \
        Ah_[buf][1] = *(const short8*)(pAh + ROWTILE + (it) * 512);          \
        Al_[buf][0] = *(const short8*)(pAl + (it) * 512);                    \
        Al_[buf][1] = *(const short8*)(pAl + ROWTILE + (it) * 512);          \
        _Pragma("unroll")                                                    \
        for (int i_ = 0; i_ < 4; ++i_) {                                     \
            Bh_[buf][i_] = *(const short8*)(pBh + i_ * ROWTILE + (it) * 512);\
            Bl_[buf][i_] = *(const short8*)(pBl + i_ * ROWTILE + (it) * 512);\
        }                                                                    \
    } while (0)

    LOADSET(0, 0);
#pragma unroll
    for (int it = 0; it < 8; ++it) {
        const int cur = it & 1;
        if (it < 7) LOADSET(cur ^ 1, it + 1);
#pragma unroll
        for (int ni = 0; ni < 4; ++ni) {
            acc[0][ni] = __builtin_amdgcn_mfma_f32_16x16x32_bf16(Ah_[cur][0], Bh_[cur][ni], acc[0][ni], 0, 0, 0);
            acc[0][ni] = __builtin_amdgcn_mfma_f32_16x16x32_bf16(Ah_[cur][0], Bl_[cur][ni], acc[0][ni], 0, 0, 0);
            acc[0][ni] = __builtin_amdgcn_mfma_f32_16x16x32_bf16(Al_[cur][0], Bh_[cur][ni], acc[0][ni], 0, 0, 0);
            acc[1][ni] = __builtin_amdgcn_mfma_f32_16x16x32_bf16(Ah_[cur][1], Bh_[cur][ni], acc[1][ni], 0, 0, 0);
            acc[1][ni] = __builtin_amdgcn_mfma_f32_16x16x32_bf16(Ah_[cur][1], Bl_[cur][ni], acc[1][ni], 0, 0, 0);
            acc[1][ni] = __builtin_amdgcn_mfma_f32_16x16x32_bf16(Al_[cur][1], Bh_[cur][ni], acc[1][ni], 0, 0, 0);
        }
    }
#undef LOADSET

    // dump wave tiles to LDS (C/D layout: col(n)=lane&15, row(m)=quad*4+reg)
#pragma unroll
    for (int mi = 0; mi < 2; ++mi) {
#pragma unroll
        for (int ni = 0; ni < 4; ++ni) {
#pragma unroll
            for (int rr = 0; rr < 4; ++rr) {
                red[w][(mi * 16 + quad * 4 + rr) * 68 + ni * 16 + m16] = acc[mi][ni][rr];
            }
        }
    }
    __syncthreads();

    // reduce the 8 K-chunk waves + bias + tanh.
    // thread t -> m_l = t>>4 (0..31), n_l = (t&15)*4
    const int m_l  = t >> 4;
    const int n_l  = (t & 15) * 4;
    const int base = m_l * 68 + n_l;
    float s0 = 0.f, s1 = 0.f, s2 = 0.f, s3 = 0.f;
#pragma unroll
    for (int ww = 0; ww < 8; ++ww) {
        float4 v = *(const float4*)&red[ww][base];
        s0 += v.x; s1 += v.y; s2 += v.z; s3 += v.w;
    }
    float4 b0 = *(const float4*)(bias + n0 + n_l);
    float4 o0;
    o0.x = tanhf(s0 + b0.x);
    o0.y = tanhf(s1 + b0.y);
    o0.z = tanhf(s2 + b0.z);
    o0.w = tanhf(s3 + b0.w);
    *(float4*)(out + (size_t)(m0 + m_l) * Ddim + n0 + n_l) = o0;
}

extern "C" void kernel_launch(void* const* d_in, const int* in_sizes, int n_in,
                              void* d_out, int out_size, void* d_ws, size_t ws_size,
                              hipStream_t stream) {
    // inputs (fp32 unless noted): x (dead for returned row), feat[256*32*2048],
    // label[256*32] (int32), W[2048*2048], b[2048]
    const float* feat  = (const float*)d_in[1];
    const int*   label = (const int*)d_in[2];
    const float* W     = (const float*)d_in[3];
    const float* bias  = (const float*)d_in[4];
    float*       out   = (float*)d_out;

    char* ws = (char*)d_ws;
    ushort_t* s_hi  = (ushort_t*)ws;                 // 1 MB
    ushort_t* s_lo  = (ushort_t*)(ws + (1u << 20));  // 1 MB
    ushort_t* WT_hi = (ushort_t*)(ws + (2u << 20));  // 8 MB
    ushort_t* WT_lo = (ushort_t*)(ws + (10u << 20)); // 8 MB

    k_prep<<<dim3(1536), dim3(256), 0, stream>>>(feat, label, W, s_hi, s_lo, WT_hi, WT_lo);
    k_gemm2<<<dim3(256), dim3(512), 0, stream>>>(s_hi, s_lo, WT_hi, WT_lo, bias, out);
}

// Round 3
// 127.376 us; speedup vs baseline: 1.2234x; 1.0087x over previous
//
#include <hip/hip_runtime.h>
#include <hip/hip_bf16.h>

typedef unsigned short ushort_t;
using ushort4v = __attribute__((ext_vector_type(4))) ushort_t;
using ushort8 = __attribute__((ext_vector_type(8))) ushort_t;
using short8  = __attribute__((ext_vector_type(8))) short;
using float4v = __attribute__((ext_vector_type(4))) float;

#define Bsz 256
#define Aattr 32
#define Ddim 2048

// Tiled operand layout ("fragment-ordered"): X_t[row/16][k/32][16][32] bf16.
// Element (row r, k c) lives at ((r>>4)*(Ddim/32) + (c>>5))*512 + (r&15)*32 + (c&31).
// A wave's MFMA frag load (lane = m16,quad reads [m16][quad*8+j]) is then ONE
// contiguous 1KB transaction instead of 16 lines scattered at 4KB stride.
#define KT (Ddim / 32)          // 64 k-tiles per 16-row tile
#define ROWTILE (KT * 512)      // elements per 16-row tile = 32768

__device__ __forceinline__ float bf2f(ushort_t u) {
    union { unsigned int i; float f; } c;
    c.i = ((unsigned int)u) << 16;
    return c.f;
}

__device__ __forceinline__ ushort_t f2bf(float f) {
    union { float f; unsigned int i; } c;
    c.f = f;
    unsigned int x = c.i;
    unsigned int r = (x + 0x7FFFu + ((x >> 16) & 1u)) >> 16;  // RNE
    return (ushort_t)r;
}

struct BfPair { ushort_t hi, lo; };
__device__ __forceinline__ BfPair split_bf16(float x) {
    BfPair p;
    p.hi = f2bf(x);
    p.lo = f2bf(x - bf2f(p.hi));
    return p;
}

__device__ __forceinline__ size_t tiled_off(int row, int k) {
    return (size_t)((row >> 4) * KT + (k >> 5)) * 512 + (row & 15) * 32 + (k & 31);
}

// ---------------------------------------------------------------------------
// Kernel 1 (fused prep): two independent BW-bound jobs in one dispatch.
//   blocks [0, 512):   masked attribute reduction -> S hi/lo (tiled layout)
//   blocks [512,1536): W fp32 [d][e] -> WT hi/lo bf16 tiled [e-tiles][k-tiles]
// (unchanged from round 2)
// ---------------------------------------------------------------------------
__global__ __launch_bounds__(256) void k_prep(
    const float* __restrict__ feat, const int* __restrict__ label,
    const float* __restrict__ W,
    ushort_t* __restrict__ s_hi, ushort_t* __restrict__ s_lo,
    ushort_t* __restrict__ WT_hi, ushort_t* __restrict__ WT_lo) {
    __shared__ float tile[64][65];   // wt path; reduce path reuses as int[]
    const int t = threadIdx.x;

    if (blockIdx.x < 512) {
        // ---- reduce path: b = id>>1, half = id&1 ----
        int* list = (int*)&tile[0][0];
        int* cntp = (int*)&tile[1][0];
        const int b    = blockIdx.x >> 1;
        const int half = blockIdx.x & 1;

        if (t < 64) {
            int lab = label[b * Aattr + (t & 31)];
            unsigned long long vote = __ballot(lab > 0);
            unsigned m32 = (unsigned)(vote & 0xFFFFFFFFull);
            if (t < 32) {
                if (lab > 0) {
                    int rank = __popc(m32 & ((1u << t) - 1u));
                    list[rank] = t;
                }
                if (t == 0) *cntp = __popc(m32);
            }
        }
        __syncthreads();

        const int n  = *cntp;
        const int d0 = half * 1024 + t * 4;
        const float* fb = feat + (size_t)b * (Aattr * Ddim) + d0;

        float a0 = 0.f, a1 = 0.f, a2 = 0.f, a3 = 0.f;
        int i = 0;
        for (; i + 4 <= n; i += 4) {
            const int j0 = list[i], j1 = list[i+1], j2 = list[i+2], j3 = list[i+3];
            float4 v0 = *(const float4*)(fb + j0 * Ddim);
            float4 v1 = *(const float4*)(fb + j1 * Ddim);
            float4 v2 = *(const float4*)(fb + j2 * Ddim);
            float4 v3 = *(const float4*)(fb + j3 * Ddim);
            a0 += v0.x + v1.x + v2.x + v3.x;
            a1 += v0.y + v1.y + v2.y + v3.y;
            a2 += v0.z + v1.z + v2.z + v3.z;
            a3 += v0.w + v1.w + v2.w + v3.w;
        }
        for (; i < n; ++i) {
            float4 v = *(const float4*)(fb + list[i] * Ddim);
            a0 += v.x; a1 += v.y; a2 += v.z; a3 += v.w;
        }

        ushort4v hi, lo;
        BfPair p0 = split_bf16(a0); hi[0] = p0.hi; lo[0] = p0.lo;
        BfPair p1 = split_bf16(a1); hi[1] = p1.hi; lo[1] = p1.lo;
        BfPair p2 = split_bf16(a2); hi[2] = p2.hi; lo[2] = p2.lo;
        BfPair p3 = split_bf16(a3); hi[3] = p3.hi; lo[3] = p3.lo;
        const size_t off = tiled_off(b, d0);   // d0..d0+3 stay in one 32-k tile
        *(ushort4v*)(s_hi + off) = hi;
        *(ushort4v*)(s_lo + off) = lo;
    } else {
        // ---- transpose+split path ----
        const int q  = blockIdx.x - 512;
        const int bx = q & 31;        // e-tile
        const int by = q >> 5;        // d-tile

#pragma unroll
        for (int p = 0; p < 4; ++p) {
            const int row = p * 16 + (t >> 4);
            const int c   = (t & 15) * 4;
            float4 v = *(const float4*)(W + (size_t)(by * 64 + row) * Ddim + bx * 64 + c);
            tile[row][c + 0] = v.x;
            tile[row][c + 1] = v.y;
            tile[row][c + 2] = v.z;
            tile[row][c + 3] = v.w;
        }
        __syncthreads();
#pragma unroll
        for (int p = 0; p < 2; ++p) {
            const int er = p * 32 + (t >> 3);
            const int dc = (t & 7) * 8;
            ushort8 hi, lo;
#pragma unroll
            for (int j = 0; j < 8; ++j) {
                BfPair pr = split_bf16(tile[dc + j][er]);
                hi[j] = pr.hi; lo[j] = pr.lo;
            }
            // row e = bx*64+er, k = by*64+dc (8 consecutive k in one 32-tile)
            const size_t off = tiled_off(bx * 64 + er, by * 64 + dc);
            *(ushort8*)(WT_hi + off) = hi;
            *(ushort8*)(WT_lo + off) = lo;
        }
    }
}

// ---------------------------------------------------------------------------
// Kernel 2: fused GEMM + K-reduce + bias + tanh.
// Geometry: 256 blocks (1/CU) x 8 waves. Block tile 32(m)x64(n), K-split 8.
// ROUND-3 CHANGE: prefetch distance 2 (three rotating register buffer sets,
// statically indexed under full unroll). Per-iteration MFMA cover is only
// ~120-190 cyc but L2-hit latency is ~200-300 cyc; prefetch-1 left every
// iteration stalled on vmcnt with just 2 waves/SIMD of TLP. Two iterations
// of cover (~240-380 cyc) >= L2 latency. VGPR: 3x12x4=144 buf + 32 acc +
// addressing ~= 195 < 256 -> still 8 waves/CU.
// ---------------------------------------------------------------------------
__global__ __launch_bounds__(512, 2) void k_gemm2(
    const ushort_t* __restrict__ S_hi, const ushort_t* __restrict__ S_lo,
    const ushort_t* __restrict__ WT_hi, const ushort_t* __restrict__ WT_lo,
    const float* __restrict__ bias, float* __restrict__ out) {
    __shared__ float red[8][32 * 68];   // 69632 B

    const int g      = blockIdx.x;
    const int q      = g >> 3;
    const int n_tile = (g & 7) * 4 + (q & 3);   // [0,32)
    const int m_tile = q >> 2;                  // [0,8)
    const int m0     = m_tile * 32;
    const int n0     = n_tile * 64;

    const int t    = threadIdx.x;
    const int w    = t >> 6;          // wave id 0..7 = K-chunk
    const int l    = t & 63;
    const int quad = l >> 4;
    const int m16  = l & 15;

    float4v acc[2][4];
#pragma unroll
    for (int i = 0; i < 2; ++i)
#pragma unroll
        for (int j = 0; j < 4; ++j) acc[i][j] = {0.f, 0.f, 0.f, 0.f};

    // Wave base pointers into tiled operands. kt0 = w*8 (8 k-tiles per wave).
    const int lane_off = m16 * 32 + quad * 8;
    const size_t abase = (size_t)((m0 >> 4) * KT + w * 8) * 512 + lane_off;
    const size_t bbase = (size_t)((n0 >> 4) * KT + w * 8) * 512 + lane_off;
    const ushort_t* pAh = S_hi + abase;
    const ushort_t* pAl = S_lo + abase;
    const ushort_t* pBh = WT_hi + bbase;
    const ushort_t* pBl = WT_lo + bbase;

    short8 Ah_[3][2], Al_[3][2], Bh_[3][4], Bl_[3][4];

#define LOADSET(buf, it)                                                     \
    do {                                                                     \
        Ah_[buf][0] = *(const short8*)(pAh + (it) * 512);                    \
        Ah_[buf][1] = *(const short8*)(pAh + ROWTILE + (it) * 512);          \
        Al_[buf][0] = *(const short8*)(pAl + (it) * 512);                    \
        Al_[buf][1] = *(const short8*)(pAl + ROWTILE + (it) * 512);          \
        _Pragma("unroll")                                                    \
        for (int i_ = 0; i_ < 4; ++i_) {                                     \
            Bh_[buf][i_] = *(const short8*)(pBh + i_ * ROWTILE + (it) * 512);\
            Bl_[buf][i_] = *(const short8*)(pBl + i_ * ROWTILE + (it) * 512);\
        }                                                                    \
    } while (0)

    LOADSET(0, 0);
    LOADSET(1, 1);
#pragma unroll
    for (int it = 0; it < 8; ++it) {
        const int cur = it % 3;
        if (it < 6) {
            const int nxt = (it + 2) % 3;
            LOADSET(nxt, it + 2);
        }
#pragma unroll
        for (int ni = 0; ni < 4; ++ni) {
            acc[0][ni] = __builtin_amdgcn_mfma_f32_16x16x32_bf16(Ah_[cur][0], Bh_[cur][ni], acc[0][ni], 0, 0, 0);
            acc[0][ni] = __builtin_amdgcn_mfma_f32_16x16x32_bf16(Ah_[cur][0], Bl_[cur][ni], acc[0][ni], 0, 0, 0);
            acc[0][ni] = __builtin_amdgcn_mfma_f32_16x16x32_bf16(Al_[cur][0], Bh_[cur][ni], acc[0][ni], 0, 0, 0);
            acc[1][ni] = __builtin_amdgcn_mfma_f32_16x16x32_bf16(Ah_[cur][1], Bh_[cur][ni], acc[1][ni], 0, 0, 0);
            acc[1][ni] = __builtin_amdgcn_mfma_f32_16x16x32_bf16(Ah_[cur][1], Bl_[cur][ni], acc[1][ni], 0, 0, 0);
            acc[1][ni] = __builtin_amdgcn_mfma_f32_16x16x32_bf16(Al_[cur][1], Bh_[cur][ni], acc[1][ni], 0, 0, 0);
        }
    }
#undef LOADSET

    // dump wave tiles to LDS (C/D layout: col(n)=lane&15, row(m)=quad*4+reg)
#pragma unroll
    for (int mi = 0; mi < 2; ++mi) {
#pragma unroll
        for (int ni = 0; ni < 4; ++ni) {
#pragma unroll
            for (int rr = 0; rr < 4; ++rr) {
                red[w][(mi * 16 + quad * 4 + rr) * 68 + ni * 16 + m16] = acc[mi][ni][rr];
            }
        }
    }
    __syncthreads();

    // reduce the 8 K-chunk waves + bias + tanh.
    // thread t -> m_l = t>>4 (0..31), n_l = (t&15)*4
    const int m_l  = t >> 4;
    const int n_l  = (t & 15) * 4;
    const int base = m_l * 68 + n_l;
    float s0 = 0.f, s1 = 0.f, s2 = 0.f, s3 = 0.f;
#pragma unroll
    for (int ww = 0; ww < 8; ++ww) {
        float4 v = *(const float4*)&red[ww][base];
        s0 += v.x; s1 += v.y; s2 += v.z; s3 += v.w;
    }
    float4 b0 = *(const float4*)(bias + n0 + n_l);
    float4 o0;
    o0.x = tanhf(s0 + b0.x);
    o0.y = tanhf(s1 + b0.y);
    o0.z = tanhf(s2 + b0.z);
    o0.w = tanhf(s3 + b0.w);
    *(float4*)(out + (size_t)(m0 + m_l) * Ddim + n0 + n_l) = o0;
}

extern "C" void kernel_launch(void* const* d_in, const int* in_sizes, int n_in,
                              void* d_out, int out_size, void* d_ws, size_t ws_size,
                              hipStream_t stream) {
    // inputs (fp32 unless noted): x (dead for returned row), feat[256*32*2048],
    // label[256*32] (int32), W[2048*2048], b[2048]
    const float* feat  = (const float*)d_in[1];
    const int*   label = (const int*)d_in[2];
    const float* W     = (const float*)d_in[3];
    const float* bias  = (const float*)d_in[4];
    float*       out   = (float*)d_out;

    char* ws = (char*)d_ws;
    ushort_t* s_hi  = (ushort_t*)ws;                 // 1 MB
    ushort_t* s_lo  = (ushort_t*)(ws + (1u << 20));  // 1 MB
    ushort_t* WT_hi = (ushort_t*)(ws + (2u << 20));  // 8 MB
    ushort_t* WT_lo = (ushort_t*)(ws + (10u << 20)); // 8 MB

    k_prep<<<dim3(1536), dim3(256), 0, stream>>>(feat, label, W, s_hi, s_lo, WT_hi, WT_lo);
    k_gemm2<<<dim3(256), dim3(512), 0, stream>>>(s_hi, s_lo, WT_hi, WT_lo, bias, out);
}